// Round 7
// baseline (1901.973 us; speedup 1.0000x reference)
//
#include <hip/hip_runtime.h>
#include <hip/hip_fp16.h>

// Problem constants
#define BB 128
#define SS 512
#define EE 16
#define HH 256
#define G3 768
#define VV 256

typedef _Float16 half8 __attribute__((ext_vector_type(8)));
typedef _Float16 half4_t __attribute__((ext_vector_type(4)));
typedef float f32x4 __attribute__((ext_vector_type(4)));

// ---------------------------------------------------------------------------
// P: swizzle W_hh [256][768] and W_out [256][256] (fp32, row=K, col=N) into
// fp16 MFMA B-fragment order: flat idx = ((n_tile*8 + k_tile)*64 + lane)*8 + j
//   = n*4096 + k*512 + L*8 + j
// holding W[k_tile*32 + (lane>>4)*8 + j][n_tile*16 + (lane&15)].
// ---------------------------------------------------------------------------
__global__ __launch_bounds__(256) void swizzle_weights(
    const float* __restrict__ Whh, const float* __restrict__ Wout,
    _Float16* __restrict__ whh_swz, _Float16* __restrict__ wout_swz) {
  int t = blockIdx.x * 256 + threadIdx.x;
  if (t < 48 * 8 * 64 * 8) {  // 196608 elements of W_hh
    int j = t & 7, L = (t >> 3) & 63, k = (t >> 9) & 7, n = t >> 12;
    int row = k * 32 + (L >> 4) * 8 + j;
    int col = n * 16 + (L & 15);
    whh_swz[t] = (_Float16)Whh[row * G3 + col];
  }
  if (t < 16 * 8 * 64 * 8) {  // 65536 elements of W_out
    int j = t & 7, L = (t >> 3) & 63, k = (t >> 9) & 7, n = t >> 12;
    int row = k * 32 + (L >> 4) * 8 + j;
    int col = n * 16 + (L & 15);
    wout_swz[t] = (_Float16)Wout[row * VV + col];
  }
}

// ---------------------------------------------------------------------------
// K1: gi = emb[x] @ W_ih + b_ih (+ b_hh folded for r,z gates), written fp16 in
// the swizzled per-(batch-group, t) layout K2's lanes read with 8B loads.
// ---------------------------------------------------------------------------
__global__ __launch_bounds__(256) void gi_kernel(
    const int* __restrict__ x, const float* __restrict__ embed,
    const float* __restrict__ W_ih, const float* __restrict__ b_ih,
    const float* __restrict__ b_hh, _Float16* __restrict__ gi_swz) {
  int gid = blockIdx.x;          // 0..1023
  int bg = gid >> 7;             // batch group 0..7
  int t0 = (gid & 127) * 4;      // 4 timesteps per block
  int tid = threadIdx.x;

  __shared__ __align__(16) float s_wih[EE * G3];      // 48 KB
  __shared__ __align__(16) float s_bias[G3];          // 3 KB
  __shared__ __align__(16) float s_emb16[4][16][EE];  // 4 KB
  __shared__ int s_x[4][16];

  for (int i = tid; i < EE * G3; i += 256) s_wih[i] = W_ih[i];
  for (int i = tid; i < G3; i += 256)
    s_bias[i] = b_ih[i] + (i < 512 ? b_hh[i] : 0.0f);  // fold b_hh for r,z only
  if (tid < 64) {
    int tt = tid >> 4, m = tid & 15;
    s_x[tt][m] = x[(bg * 16 + m) * SS + t0 + tt];
  }
  __syncthreads();
  for (int i = tid; i < 4 * 16 * EE; i += 256) {
    int tt = i >> 8, m = (i >> 4) & 15, e = i & 15;
    s_emb16[tt][m][e] = embed[s_x[tt][m] * EE + e];
  }
  __syncthreads();

  for (int cch = 0; cch < 3; cch++) {
    int gc = cch * 256 + tid;  // gate column
    float w[EE];
#pragma unroll
    for (int e = 0; e < EE; e++) w[e] = s_wih[e * G3 + gc];
    float bias = s_bias[gc];
    int wi = (gc >> 4) & 15, cc = gc & 15;
    int tilebase = (cch * 16 + wi) * 64;
    for (int tt = 0; tt < 4; tt++) {
      size_t gbase = (size_t)(bg * 512 + t0 + tt) * 12288;
#pragma unroll
      for (int mq = 0; mq < 4; mq++) {
        half4_t v;
#pragma unroll
        for (int r = 0; r < 4; r++) {
          int m = mq * 4 + r;
          float acc = bias;
#pragma unroll
          for (int e = 0; e < EE; e++) acc += s_emb16[tt][m][e] * w[e];
          v[r] = (_Float16)acc;
        }
        *(half4_t*)(gi_swz + gbase + (size_t)((tilebase + mq * 16 + cc) * 4)) = v;
      }
    }
  }
}

// ---------------------------------------------------------------------------
// K2: GRU recurrence. 8 blocks x 1024 threads (16 waves, 4 waves/SIMD).
// R11: wN B-fragments out of registers (broke the R7-R10 register cliff),
// R12: LDS-only barrier drain + register-carried hp (flat -> proved the
// step is pipe-floor-bound, not stall-bound).
//
// R13: wN moves LDS -> L2 (global).  Step budget at R12 (5590cy): LDS pipe
// ~3100-3500cy of which HALF is the wN stream (128 x ds_read_b128 = 128KB
// disjoint per step); av reads (the other 128KB) are structurally
// irreducible (every wave needs the full h tile for its N-tiles).  wN is
// time-invariant and per-block only 128KB = resident in the block's XCD L2
// after step 0.  Reading it with global_load_dwordx4 (addr = SGPR base +
// L*16 + k*1024 immediate) moves 128KB/step from the lgkmcnt pipe to the
// nearly-idle vmcnt pipe; 4-wave TLP hides the ~200cy L2 latency.  LDS
// drops to ~140KB/step (~1700cy), VMEM gains ~2200cy at L2-hit BW - both
// below the old LDS ceiling, and on different pipes.
// Tripwires: WRITE_SIZE exactly 32768KB; FETCH_SIZE ~unchanged (wN L2-hot;
// growth = L2 thrash and the theory is wrong).
// LDS: 16.9 KB (h double-buffer only).
// ---------------------------------------------------------------------------
__global__ void __launch_bounds__(1024)
__attribute__((amdgpu_waves_per_eu(4, 4)))
gru_kernel(
    const _Float16* __restrict__ gi_swz, const _Float16* __restrict__ whh_swz,
    const float* __restrict__ b_hh, _Float16* __restrict__ h_seq) {
  int bg = blockIdx.x;  // 0..7
  int tid = threadIdx.x;
  int w = tid >> 6, L = tid & 63;
  int q = L >> 4, c = L & 15;

  __shared__ __align__(16) _Float16 s_h[2][16][264];  // 16.9 KB

  // r,z B fragments for this wave's column tile, in registers (64 VGPR).
  half8 wR[8], wZ[8];
#pragma unroll
  for (int k = 0; k < 8; k++) {
    wR[k] = *(const half8*)(whh_swz + (((size_t)((0 * 16 + w) * 8 + k) * 64 + L) * 8));
    wZ[k] = *(const half8*)(whh_swz + (((size_t)((1 * 16 + w) * 8 + k) * 64 + L) * 8));
  }
  // n-gate B-fragment stream: L2-resident, read per k-step inside the loop.
  // n-tile (2*16+w), k, lane L lives at 131072 + w*4096 + k*512 + L*8.
  const _Float16* wnG = whh_swz + 131072 + w * 4096 + L * 8;

  // n-gate hidden bias (multiplied by r inside the step)
  float bhn = b_hh[512 + w * 16 + c];

  // zero both h buffers (h0 = 0): 8448 halves = 4224 uints
  for (int idx = tid; idx < (2 * 16 * 264) / 2; idx += 1024)
    ((unsigned int*)s_h)[idx] = 0u;
  __syncthreads();

  // lane's own h_{t-1} C-fragment, register-carried (h0 = 0); bit-identical
  // to re-reading the stored fp16 from LDS.
  half4_t hp = {(_Float16)0.f, (_Float16)0.f, (_Float16)0.f, (_Float16)0.f};

  int col = w * 16 + c;
  // h_seq flat offset (halves) for (batch row bg*16 + q*4, t=0, col)
  unsigned hoff = (unsigned)(bg * 16 + q * 4) * (SS * HH) + (unsigned)col;
  // gi offset for this lane (advance by 12288/step)
  unsigned gioff = (unsigned)(bg * 512) * 12288u + (unsigned)((w * 64 + L) * 4);

  const _Float16* hsrc = &s_h[0][0][0];
  _Float16* hdst = &s_h[1][0][0];
  const int aoff = c * 264 + q * 8;             // av base (halves)
  const int woff = (q * 4) * 264 + col;         // h-write base (halves)

#pragma unroll 1
  for (int t = 0; t < SS; t++) {
    // gate-input loads (global; issued early, consumed in epilogue)
    half4_t giR = *(const half4_t*)(gi_swz + gioff);
    half4_t giZ = *(const half4_t*)(gi_swz + gioff + 4096u);
    half4_t giN = *(const half4_t*)(gi_swz + gioff + 8192u);

    f32x4 aR = {0.f, 0.f, 0.f, 0.f}, aZ = aR, aN = aR;
#pragma unroll
    for (int k = 0; k < 8; k++) {
      half8 av = *(const half8*)(hsrc + aoff + k * 32);   // A[m=c][k*32+q*8+j]
      half8 wNk = *(const half8*)(wnG + k * 512);         // L2-hot global
      aR = __builtin_amdgcn_mfma_f32_16x16x32_f16(av, wR[k], aR, 0, 0, 0);
      aZ = __builtin_amdgcn_mfma_f32_16x16x32_f16(av, wZ[k], aZ, 0, 0, 0);
      aN = __builtin_amdgcn_mfma_f32_16x16x32_f16(av, wNk, aN, 0, 0, 0);
    }

#pragma unroll
    for (int r = 0; r < 4; r++) {
      float rg = aR[r] + (float)giR[r];
      rg = 1.f / (1.f + __expf(-rg));
      float zg = aZ[r] + (float)giZ[r];
      zg = 1.f / (1.f + __expf(-zg));
      float ng = (float)giN[r] + rg * (aN[r] + bhn);
      ng = 2.f / (1.f + __expf(-2.f * ng)) - 1.f;  // tanh
      float hn = (1.f - zg) * ng + zg * (float)hp[r];
      _Float16 h16 = (_Float16)hn;
      hp[r] = h16;
      hdst[woff + r * 264] = h16;
      h_seq[(size_t)(hoff + (unsigned)r * 131072u)] = h16;
    }

    // LDS-only drain + raw barrier: h_seq stores, gi and wN streams stay in
    // flight across the barrier (no vmcnt(0) — the __syncthreads stall).
    asm volatile("s_waitcnt lgkmcnt(0)" ::: "memory");
    __builtin_amdgcn_s_barrier();

    const _Float16* tp = hsrc; hsrc = hdst; hdst = (_Float16*)tp;
    hoff += (unsigned)HH;
    gioff += 12288u;
  }
}

// ---------------------------------------------------------------------------
// K3: out = h_seq @ W_out + b_out via fp16 MFMA. 1024 blocks x 256 threads;
// block handles 64 bt-rows (wave w -> rows w*16..+16), full N=256 (16 tiles).
// Static LDS = 33 KB.  Output written fp32.
// ---------------------------------------------------------------------------
__global__ __launch_bounds__(256) void out_kernel(
    const _Float16* __restrict__ h_seq, const _Float16* __restrict__ wout_swz,
    const float* __restrict__ b_out, float* __restrict__ out) {
  int blk = blockIdx.x;
  int tid = threadIdx.x;
  int w = tid >> 6, L = tid & 63, q = L >> 4, c = L & 15;

  __shared__ __align__(16) _Float16 s_a[64 * 264];  // 33 KB

  const _Float16* src = h_seq + (size_t)blk * 64 * 256;
  for (int idx = tid; idx < (64 * 256) / 8; idx += 256) {
    int row = idx >> 5, kk = (idx & 31) * 8;
    *(half8*)(s_a + row * 264 + kk) = *(const half8*)(src + row * 256 + kk);
  }
  __syncthreads();

  half8 a[8];
#pragma unroll
  for (int k = 0; k < 8; k++)
    a[k] = *(const half8*)(s_a + (w * 16 + c) * 264 + k * 32 + q * 8);

  f32x4 acc[16];
#pragma unroll
  for (int n = 0; n < 16; n++) {
    f32x4 z = {0.f, 0.f, 0.f, 0.f};
    acc[n] = z;
#pragma unroll
    for (int k = 0; k < 8; k++) {
      half8 b = *(const half8*)(wout_swz + ((size_t)(n * 8 + k) * 64 + L) * 8);
      acc[n] = __builtin_amdgcn_mfma_f32_16x16x32_f16(a[k], b, acc[n], 0, 0, 0);
    }
  }
#pragma unroll
  for (int n = 0; n < 16; n++) {
    int v = n * 16 + c;
    float bo = b_out[v];
#pragma unroll
    for (int r = 0; r < 4; r++) {
      int bt = blk * 64 + w * 16 + q * 4 + r;
      out[(size_t)bt * 256 + v] = acc[n][r] + bo;
    }
  }
}

// ---------------------------------------------------------------------------
extern "C" void kernel_launch(void* const* d_in, const int* in_sizes, int n_in,
                              void* d_out, int out_size, void* d_ws, size_t ws_size,
                              hipStream_t stream) {
  const int*   x    = (const int*)d_in[0];
  const float* emb  = (const float*)d_in[1];
  const float* Wih  = (const float*)d_in[2];
  const float* bih  = (const float*)d_in[3];
  const float* Whh  = (const float*)d_in[4];
  const float* bhh  = (const float*)d_in[5];
  const float* Wout = (const float*)d_in[6];
  const float* bout = (const float*)d_in[7];

  char* ws = (char*)d_ws;
  // ws layout (134,742,016 B total):
  //   gi_swz   : 128*512*768 fp16 = 100,663,296 B
  //   whh_swz  : 196608 fp16      =     393,216 B
  //   wout_swz : 65536 fp16       =     131,072 B
  //   h_seq    : 128*512*256 fp16 =  33,554,432 B
  _Float16* gi_swz   = (_Float16*)(ws);
  _Float16* whh_swz  = (_Float16*)(ws + 100663296);
  _Float16* wout_swz = (_Float16*)(ws + 100663296 + 393216);
  _Float16* h_seq    = (_Float16*)(ws + 100663296 + 393216 + 131072);

  swizzle_weights<<<768, 256, 0, stream>>>(Whh, Wout, whh_swz, wout_swz);
  gi_kernel<<<1024, 256, 0, stream>>>(x, emb, Wih, bih, bhh, gi_swz);
  gru_kernel<<<8, 1024, 0, stream>>>(gi_swz, whh_swz, bhh, h_seq);
  out_kernel<<<1024, 256, 0, stream>>>(h_seq, wout_swz, bout, (float*)d_out);
}

// Round 8
// 1480.685 us; speedup vs baseline: 1.2845x; 1.2845x over previous
//
#include <hip/hip_runtime.h>
#include <hip/hip_fp16.h>

// Problem constants
#define BB 128
#define SS 512
#define EE 16
#define HH 256
#define G3 768
#define VV 256

typedef _Float16 half8 __attribute__((ext_vector_type(8)));
typedef _Float16 half4_t __attribute__((ext_vector_type(4)));
typedef float f32x4 __attribute__((ext_vector_type(4)));

// ---------------------------------------------------------------------------
// P: swizzle W_hh [256][768] and W_out [256][256] (fp32, row=K, col=N) into
// fp16 MFMA B-fragment order: flat idx = ((n_tile*8 + k_tile)*64 + lane)*8 + j
//   = n*4096 + k*512 + L*8 + j
// holding W[k_tile*32 + (lane>>4)*8 + j][n_tile*16 + (lane&15)].
// ---------------------------------------------------------------------------
__global__ __launch_bounds__(256) void swizzle_weights(
    const float* __restrict__ Whh, const float* __restrict__ Wout,
    _Float16* __restrict__ whh_swz, _Float16* __restrict__ wout_swz) {
  int t = blockIdx.x * 256 + threadIdx.x;
  if (t < 48 * 8 * 64 * 8) {  // 196608 elements of W_hh
    int j = t & 7, L = (t >> 3) & 63, k = (t >> 9) & 7, n = t >> 12;
    int row = k * 32 + (L >> 4) * 8 + j;
    int col = n * 16 + (L & 15);
    whh_swz[t] = (_Float16)Whh[row * G3 + col];
  }
  if (t < 16 * 8 * 64 * 8) {  // 65536 elements of W_out
    int j = t & 7, L = (t >> 3) & 63, k = (t >> 9) & 7, n = t >> 12;
    int row = k * 32 + (L >> 4) * 8 + j;
    int col = n * 16 + (L & 15);
    wout_swz[t] = (_Float16)Wout[row * VV + col];
  }
}

// ---------------------------------------------------------------------------
// K1: gi = emb[x] @ W_ih + b_ih (+ b_hh folded for r,z gates), written fp16 in
// the swizzled per-(batch-group, t) layout K2's lanes read with 8B loads.
// ---------------------------------------------------------------------------
__global__ __launch_bounds__(256) void gi_kernel(
    const int* __restrict__ x, const float* __restrict__ embed,
    const float* __restrict__ W_ih, const float* __restrict__ b_ih,
    const float* __restrict__ b_hh, _Float16* __restrict__ gi_swz) {
  int gid = blockIdx.x;          // 0..1023
  int bg = gid >> 7;             // batch group 0..7
  int t0 = (gid & 127) * 4;      // 4 timesteps per block
  int tid = threadIdx.x;

  __shared__ __align__(16) float s_wih[EE * G3];      // 48 KB
  __shared__ __align__(16) float s_bias[G3];          // 3 KB
  __shared__ __align__(16) float s_emb16[4][16][EE];  // 4 KB
  __shared__ int s_x[4][16];

  for (int i = tid; i < EE * G3; i += 256) s_wih[i] = W_ih[i];
  for (int i = tid; i < G3; i += 256)
    s_bias[i] = b_ih[i] + (i < 512 ? b_hh[i] : 0.0f);  // fold b_hh for r,z only
  if (tid < 64) {
    int tt = tid >> 4, m = tid & 15;
    s_x[tt][m] = x[(bg * 16 + m) * SS + t0 + tt];
  }
  __syncthreads();
  for (int i = tid; i < 4 * 16 * EE; i += 256) {
    int tt = i >> 8, m = (i >> 4) & 15, e = i & 15;
    s_emb16[tt][m][e] = embed[s_x[tt][m] * EE + e];
  }
  __syncthreads();

  for (int cch = 0; cch < 3; cch++) {
    int gc = cch * 256 + tid;  // gate column
    float w[EE];
#pragma unroll
    for (int e = 0; e < EE; e++) w[e] = s_wih[e * G3 + gc];
    float bias = s_bias[gc];
    int wi = (gc >> 4) & 15, cc = gc & 15;
    int tilebase = (cch * 16 + wi) * 64;
    for (int tt = 0; tt < 4; tt++) {
      size_t gbase = (size_t)(bg * 512 + t0 + tt) * 12288;
#pragma unroll
      for (int mq = 0; mq < 4; mq++) {
        half4_t v;
#pragma unroll
        for (int r = 0; r < 4; r++) {
          int m = mq * 4 + r;
          float acc = bias;
#pragma unroll
          for (int e = 0; e < EE; e++) acc += s_emb16[tt][m][e] * w[e];
          v[r] = (_Float16)acc;
        }
        *(half4_t*)(gi_swz + gbase + (size_t)((tilebase + mq * 16 + cc) * 4)) = v;
      }
    }
  }
}

// ---------------------------------------------------------------------------
// K2: GRU recurrence. 8 blocks x 1024 threads (16 waves, 4 waves/SIMD).
// Base = R12 (measured best 1193us: wN streamed from LDS, wR/wZ in regs,
// LDS-only barrier drain, register-carried hp).
//
// R14 — attack register LIVENESS, not allocation (the VALU-class busy is
// 4300cy/step vs ~1280cy of source-level VALU; the gap is consistent with
// v_accvgpr shuttle traffic forced by the fully-unrolled k-loop keeping
// 8 av half8's (32 VGPRs) + 12 acc + gi + temps live at once inside a
// 64-arch-VGPR budget):
//  a) T19 sched_group_barrier per k: {2 ds_read, 3 MFMA}. Pins the emitted
//     interleave so only ~1-2 av/wN fragments are live (8 regs vs 64
//     hoisted) -> allocator can keep acc in arch VGPRs -> shuttles die.
//  b) gi folded into MFMA C-init (aR/aZ = cvt(gi), aN = bhn): -12 epilogue
//     adds, no zero-init writes, gi regs die before the MFMA block.
//  c) blend as fma form: hn = ng + zg*(hp-ng)  (-1 op/row).
// All edits are pressure-reducing or neutral. Numerics: C-init fold is
// exact (same f32 adds, done by the MFMA's C accumulate); blend refactor
// is fp32-associativity-safe (same rounding class as before, absmax
// tolerance 3.9e-3 >> any 1-ulp delta).
// Tripwire: WRITE_SIZE must stay EXACTLY 32768 KB (growth = spill = invalid).
// LDS: 16.9 KB h double-buffer + 128 KB wN = 144.9 KB (<160 KB/WG).
// ---------------------------------------------------------------------------
__global__ void __launch_bounds__(1024)
__attribute__((amdgpu_waves_per_eu(4, 4)))
gru_kernel(
    const _Float16* __restrict__ gi_swz, const _Float16* __restrict__ whh_swz,
    const float* __restrict__ b_hh, _Float16* __restrict__ h_seq) {
  int bg = blockIdx.x;  // 0..7
  int tid = threadIdx.x;
  int w = tid >> 6, L = tid & 63;
  int q = L >> 4, c = L & 15;

  __shared__ __align__(16) _Float16 s_h[2][16][264];  // 16.9 KB
  __shared__ __align__(16) _Float16 s_wn[65536];      // 128 KB: n-gate B-frags

  // r,z B fragments for this wave's column tile, in registers (64 VGPR).
  half8 wR[8], wZ[8];
#pragma unroll
  for (int k = 0; k < 8; k++) {
    wR[k] = *(const half8*)(whh_swz + (((size_t)((0 * 16 + w) * 8 + k) * 64 + L) * 8));
    wZ[k] = *(const half8*)(whh_swz + (((size_t)((1 * 16 + w) * 8 + k) * 64 + L) * 8));
  }
  // n-gate hidden bias (multiplied by r inside the step)
  float bhn = b_hh[512 + w * 16 + c];

  // Stage n-gate fragments into LDS: s_wn[i] = whh_swz[131072 + i]
  // (n-gate tiles start at (2*16)*8*64*8 = 131072). 8 x half8 per thread,
  // coalesced global reads, stride-1 LDS writes.
  for (int i = tid; i < 8192; i += 1024)
    *(half8*)(s_wn + i * 8) = *(const half8*)(whh_swz + 131072 + (size_t)i * 8);

  // zero both h buffers (h0 = 0): 8448 halves = 4224 uints
  for (int idx = tid; idx < (2 * 16 * 264) / 2; idx += 1024)
    ((unsigned int*)s_h)[idx] = 0u;
  __syncthreads();

  // lane's own h_{t-1} C-fragment, register-carried (h0 = 0); bit-identical
  // to re-reading the stored fp16 from LDS.
  half4_t hp = {(_Float16)0.f, (_Float16)0.f, (_Float16)0.f, (_Float16)0.f};

  int col = w * 16 + c;
  // h_seq flat offset (halves) for (batch row bg*16 + q*4, t=0, col)
  unsigned hoff = (unsigned)(bg * 16 + q * 4) * (SS * HH) + (unsigned)col;
  // gi offset for this lane (advance by 12288/step)
  unsigned gioff = (unsigned)(bg * 512) * 12288u + (unsigned)((w * 64 + L) * 4);

  const _Float16* hsrc = &s_h[0][0][0];
  _Float16* hdst = &s_h[1][0][0];
  const int aoff = c * 264 + q * 8;             // av base (halves)
  const int woff = (q * 4) * 264 + col;         // h-write base (halves)
  const int wnoff = w * 4096 + L * 8;           // wN base for k=0 (halves)

#pragma unroll 1
  for (int t = 0; t < SS; t++) {
    // gate-input loads (global; consumed by the C-init fold / epilogue)
    half4_t giR = *(const half4_t*)(gi_swz + gioff);
    half4_t giZ = *(const half4_t*)(gi_swz + gioff + 4096u);
    half4_t giN = *(const half4_t*)(gi_swz + gioff + 8192u);

    // gi fold: C-init carries gi_r/gi_z (and bhn for n) into the MFMA
    // accumulate — deletes the epilogue adds, gi regs die here.
    f32x4 aR, aZ, aN;
#pragma unroll
    for (int r = 0; r < 4; r++) {
      aR[r] = (float)giR[r];
      aZ[r] = (float)giZ[r];
      aN[r] = bhn;
    }

#pragma unroll
    for (int k = 0; k < 8; k++) {
      half8 av = *(const half8*)(hsrc + aoff + k * 32);    // A[m=c][k*32+q*8+j]
      half8 wNk = *(const half8*)(s_wn + wnoff + k * 512); // stride-1, no conflict
      aR = __builtin_amdgcn_mfma_f32_16x16x32_f16(av, wR[k], aR, 0, 0, 0);
      aZ = __builtin_amdgcn_mfma_f32_16x16x32_f16(av, wZ[k], aZ, 0, 0, 0);
      aN = __builtin_amdgcn_mfma_f32_16x16x32_f16(av, wNk, aN, 0, 0, 0);
      // T19: pin per-k interleave {2 ds_read, 3 MFMA} — caps av/wN liveness
      // (~8 regs instead of 64 hoisted), freeing arch VGPRs for the accs.
      __builtin_amdgcn_sched_group_barrier(0x100, 2, 0);  // DS_READ x2
      __builtin_amdgcn_sched_group_barrier(0x008, 3, 0);  // MFMA x3
    }

#pragma unroll
    for (int r = 0; r < 4; r++) {
      float rg = 1.f / (1.f + __expf(-aR[r]));        // aR = gh_r + gi_r (+b)
      float zg = 1.f / (1.f + __expf(-aZ[r]));        // aZ = gh_z + gi_z (+b)
      float ng = (float)giN[r] + rg * aN[r];          // aN = gh_n + bhn
      ng = 2.f / (1.f + __expf(-2.f * ng)) - 1.f;     // tanh
      float hn = ng + zg * ((float)hp[r] - ng);       // (1-z)n + z*h, fma form
      _Float16 h16 = (_Float16)hn;
      hp[r] = h16;
      hdst[woff + r * 264] = h16;
      h_seq[(size_t)(hoff + (unsigned)r * 131072u)] = h16;
    }

    // LDS-only drain + raw barrier: h_seq stores and the gi stream stay in
    // flight across the barrier (no vmcnt(0) — the __syncthreads stall).
    asm volatile("s_waitcnt lgkmcnt(0)" ::: "memory");
    __builtin_amdgcn_s_barrier();

    const _Float16* tp = hsrc; hsrc = hdst; hdst = (_Float16*)tp;
    hoff += (unsigned)HH;
    gioff += 12288u;
  }
}

// ---------------------------------------------------------------------------
// K3: out = h_seq @ W_out + b_out via fp16 MFMA. 1024 blocks x 256 threads;
// block handles 64 bt-rows (wave w -> rows w*16..+16), full N=256 (16 tiles).
// Static LDS = 33 KB.  Output written fp32.
// ---------------------------------------------------------------------------
__global__ __launch_bounds__(256) void out_kernel(
    const _Float16* __restrict__ h_seq, const _Float16* __restrict__ wout_swz,
    const float* __restrict__ b_out, float* __restrict__ out) {
  int blk = blockIdx.x;
  int tid = threadIdx.x;
  int w = tid >> 6, L = tid & 63, q = L >> 4, c = L & 15;

  __shared__ __align__(16) _Float16 s_a[64 * 264];  // 33 KB

  const _Float16* src = h_seq + (size_t)blk * 64 * 256;
  for (int idx = tid; idx < (64 * 256) / 8; idx += 256) {
    int row = idx >> 5, kk = (idx & 31) * 8;
    *(half8*)(s_a + row * 264 + kk) = *(const half8*)(src + row * 256 + kk);
  }
  __syncthreads();

  half8 a[8];
#pragma unroll
  for (int k = 0; k < 8; k++)
    a[k] = *(const half8*)(s_a + (w * 16 + c) * 264 + k * 32 + q * 8);

  f32x4 acc[16];
#pragma unroll
  for (int n = 0; n < 16; n++) {
    f32x4 z = {0.f, 0.f, 0.f, 0.f};
    acc[n] = z;
#pragma unroll
    for (int k = 0; k < 8; k++) {
      half8 b = *(const half8*)(wout_swz + ((size_t)(n * 8 + k) * 64 + L) * 8);
      acc[n] = __builtin_amdgcn_mfma_f32_16x16x32_f16(a[k], b, acc[n], 0, 0, 0);
    }
  }
#pragma unroll
  for (int n = 0; n < 16; n++) {
    int v = n * 16 + c;
    float bo = b_out[v];
#pragma unroll
    for (int r = 0; r < 4; r++) {
      int bt = blk * 64 + w * 16 + q * 4 + r;
      out[(size_t)bt * 256 + v] = acc[n][r] + bo;
    }
  }
}

// ---------------------------------------------------------------------------
extern "C" void kernel_launch(void* const* d_in, const int* in_sizes, int n_in,
                              void* d_out, int out_size, void* d_ws, size_t ws_size,
                              hipStream_t stream) {
  const int*   x    = (const int*)d_in[0];
  const float* emb  = (const float*)d_in[1];
  const float* Wih  = (const float*)d_in[2];
  const float* bih  = (const float*)d_in[3];
  const float* Whh  = (const float*)d_in[4];
  const float* bhh  = (const float*)d_in[5];
  const float* Wout = (const float*)d_in[6];
  const float* bout = (const float*)d_in[7];

  char* ws = (char*)d_ws;
  // ws layout (134,742,016 B total):
  //   gi_swz   : 128*512*768 fp16 = 100,663,296 B
  //   whh_swz  : 196608 fp16      =     393,216 B
  //   wout_swz : 65536 fp16       =     131,072 B
  //   h_seq    : 128*512*256 fp16 =  33,554,432 B
  _Float16* gi_swz   = (_Float16*)(ws);
  _Float16* whh_swz  = (_Float16*)(ws + 100663296);
  _Float16* wout_swz = (_Float16*)(ws + 100663296 + 393216);
  _Float16* h_seq    = (_Float16*)(ws + 100663296 + 393216 + 131072);

  swizzle_weights<<<768, 256, 0, stream>>>(Whh, Wout, whh_swz, wout_swz);
  gi_kernel<<<1024, 256, 0, stream>>>(x, emb, Wih, bih, bhh, gi_swz);
  gru_kernel<<<8, 1024, 0, stream>>>(gi_swz, whh_swz, bhh, h_seq);
  out_kernel<<<1024, 256, 0, stream>>>(h_seq, wout_swz, bout, (float*)d_out);
}